// Round 8
// baseline (205.553 us; speedup 1.0000x reference)
//
#include <hip/hip_runtime.h>
#include <hip/hip_bf16.h>

#define NXC 440
#define NYC 500
#define GCELLS (NXC * NYC)              // 220000 (NZ = 1)
#define NWORDS ((GCELLS + 31) / 32)     // 6875 bitmap words
#define NWP 6876                        // NWORDS padded to %4 (uint4 init)
#define MAXV 40000
#define MAXP 32
#define SCANB ((NWORDS + 255) / 256)    // 27 blocks for word-sliced kernels
#define TPAD 16                         // ticket stride (ints): 1 counter / 64B line
#define CELLG 512                       // k_cell blocks (1024 thr)
#define NSEG 16                         // segment bitmaps spread atomic traffic
#define ZEROB 64                        // k_zero blocks (segbm memset only)

// Expected outputs are bf16-quantized but stored as fp32: round-trip.
__device__ __forceinline__ float bf16r(float x) {
    return __bfloat162float(__float2bfloat16(x));
}

// Linear cell index exactly as the reference (fp32 ops). Invalid -> -1.
__device__ __forceinline__ int cell_of(float x, float y, float z) {
    bool valid = (x >= 0.0f) && (x < 70.4f) &&
                 (y >= -40.0f) && (y < 40.0f) &&
                 (z >= -3.0f) && (z < 1.0f);
    if (!valid) return -1;
    int cx = (int)floorf(x / 0.16f);
    int cy = (int)floorf((y + 40.0f) / 0.16f);
    // z in [-3,1) -> cz == 0 always (NZ = 1)
    cx = min(max(cx, 0), NXC - 1);
    cy = min(max(cy, 0), NYC - 1);
    return cy * NXC + cx;
}

// Zero segment bitmaps only (440 KB; must precede k_cell's atomics).
// ticket zeroing folded into k_cell (consumed two launches later).
__global__ __launch_bounds__(256) void k_zero(unsigned* segbm) {
    int tid = blockIdx.x * 256 + threadIdx.x;
    uint4* s4 = (uint4*)segbm;
    for (int i = tid; i < NSEG * NWP / 4; i += ZEROB * 256)
        s4[i] = make_uint4(0u, 0u, 0u, 0u);
}

// Pass 1: direct fire-and-forget atomicOr into one of NSEG segment bitmaps.
// Rationale: with 4096 pts/block into 220k cells the old LDS bitmap deduped
// almost nothing (~3900 distinct words/block), so the flush issued the same
// ~2M global atomics anyway -- the LDS stage (zero + 2M LDS atomics + 2
// barriers + flush scan) was pure overhead. Direct atomics are spread over
// the whole kernel (~18 hits/word-copy, no return -> no waitcnt), unlike
// R2's end-burst 170-way pileup. Also zero-inits ticket (stream-order
// visibility; consumed by k_scatter two launches later).
__global__ __launch_bounds__(1024) void k_cell(const float* pts, int* cellid,
                                               unsigned* segbm, int* ticket, int n) {
    int tid = blockIdx.x * 1024 + threadIdx.x;
    int nq = n >> 2;                    // groups of 4 points
    int stride = CELLG * 1024;
    unsigned* myseg = segbm + (size_t)(blockIdx.x & (NSEG - 1)) * NWP;
    const float4* p4 = (const float4*)pts;
    for (int q = tid; q < nq; q += stride) {
        float4 f0 = p4[q * 5 + 0];      // floats 0..3   (pt0 xyzw0)
        float4 f1 = p4[q * 5 + 1];      // floats 4..7
        float4 f2 = p4[q * 5 + 2];      // floats 8..11
        float4 f3 = p4[q * 5 + 3];      // floats 12..15
        float4 f4 = p4[q * 5 + 4];      // floats 16..19
        int c0 = cell_of(f0.x, f0.y, f0.z);   // floats 0,1,2
        int c1 = cell_of(f1.y, f1.z, f1.w);   // floats 5,6,7
        int c2 = cell_of(f2.z, f2.w, f3.x);   // floats 10,11,12
        int c3 = cell_of(f3.w, f4.x, f4.y);   // floats 15,16,17
        if (cellid) ((int4*)cellid)[q] = make_int4(c0, c1, c2, c3);
        if (c0 >= 0) atomicOr(&myseg[c0 >> 5], 1u << (c0 & 31));
        if (c1 >= 0) atomicOr(&myseg[c1 >> 5], 1u << (c1 & 31));
        if (c2 >= 0) atomicOr(&myseg[c2 >> 5], 1u << (c2 & 31));
        if (c3 >= 0) atomicOr(&myseg[c3 >> 5], 1u << (c3 & 31));
    }
    // tail (n % 4 != 0): handled scalar by one thread
    if (tid == 0) {
        for (int i = nq * 4; i < n; ++i) {
            const float* p = pts + (size_t)i * 5;
            int c = cell_of(p[0], p[1], p[2]);
            if (cellid) cellid[i] = c;
            if (c >= 0) atomicOr(&segbm[c >> 5], 1u << (c & 31));
        }
    }
    // folded ticket zero-init (consumed by k_scatter, 2 launches later)
    {
        int4* t4 = (int4*)ticket;
        int tot4 = MAXV * TPAD / 4;
        for (int i = tid; i < tot4; i += stride)
            t4[i] = make_int4(0, 0, 0, 0);
    }
}

// Word-level exclusive scan. occ word w = OR of the 16 segment bitmaps
// (computed on the fly; segbm is 440 KB, L2-resident). Self-computed
// cross-block base -> fused (prefix, occword) int2 table; emit coords.
__global__ __launch_bounds__(256) void k_scan(const unsigned* segbm,
                                              int2* wp2, float* out_coords) {
    int b = blockIdx.x, t = threadIdx.x;
    // cross-block base: popcount of OR'd words before this block's slice
    __shared__ int sb[256];
    int pre = 0;
    const uint4* s4 = (const uint4*)segbm;      // seg s at offset s*(NWP/4)
    for (int i = t; i < b * 64; i += 256) {
        uint4 o = make_uint4(0u, 0u, 0u, 0u);
        #pragma unroll
        for (int s = 0; s < NSEG; ++s) {
            uint4 v = s4[(size_t)s * (NWP / 4) + i];
            o.x |= v.x; o.y |= v.y; o.z |= v.z; o.w |= v.w;
        }
        pre += __popc(o.x) + __popc(o.y) + __popc(o.z) + __popc(o.w);
    }
    sb[t] = pre;
    __syncthreads();
    for (int d = 128; d > 0; d >>= 1) {
        if (t < d) sb[t] += sb[t + d];
        __syncthreads();
    }
    int base = sb[0];
    // intra-block scan over this slice
    int w = b * 256 + t;
    unsigned o = 0u;
    if (w < NWORDS) {
        #pragma unroll
        for (int s = 0; s < NSEG; ++s) o |= segbm[(size_t)s * NWP + w];
    }
    int c = __popc(o);
    __shared__ int s[256];
    s[t] = c;
    __syncthreads();
    for (int d = 1; d < 256; d <<= 1) {
        int v = (t >= d) ? s[t - d] : 0;
        __syncthreads();
        s[t] += v;
        __syncthreads();
    }
    int vid = base + (s[t] - c);
    if (w < NWORDS) {
        wp2[w] = make_int2(vid, (int)o);
        if (vid < MAXV) {
            unsigned m = o;
            while (m) {
                int bit = __ffs(m) - 1;
                m &= m - 1u;
                if (vid < MAXV) {
                    int cell = w * 32 + bit;
                    int cy = cell / NXC, cx = cell - cy * NXC;
                    float* oc = out_coords + (size_t)vid * 3;
                    oc[0] = 0.0f;
                    oc[1] = bf16r((float)cy);
                    oc[2] = bf16r((float)cx);
                }
                ++vid;
            }
        }
    }
}

__device__ __forceinline__ void scat1(int cell, int i, const int2* wp2,
                                      int* ticket, int* seg, int S) {
    if (cell < 0) return;
    int w = cell >> 5, b = cell & 31;
    int2 t2 = wp2[w];                   // 8B L2 load (55 KB table, L2-hot)
    int vid = t2.x + __popc(((unsigned)t2.y) & ((1u << b) - 1u));
    if (vid >= MAXV) return;
    int t = atomicAdd(&ticket[(size_t)vid * TPAD], 1);
    if (t < S) seg[(size_t)vid * S + t] = i;
}

// Scatter point indices into fixed-stride per-voxel segments, 8 pts/thread
// via 2x int4 cellid loads (8 independent lookup->atomic chains: latency ILP
// hides the L2 lookups -- R6's LDS-cached variant was neutral-to-negative).
__global__ __launch_bounds__(256) void k_scatter(const float* pts, const int* cellid,
                                                 const int2* wp2,
                                                 int* ticket, int* seg, int S, int n) {
    int g = blockIdx.x * 256 + threadIdx.x;
    int n8 = n >> 3;
    if (cellid) {
        if (g < n8) {
            const int4* c4 = (const int4*)cellid;
            int4 ca = c4[g * 2], cb = c4[g * 2 + 1];
            int i0 = g * 8;
            scat1(ca.x, i0 + 0, wp2, ticket, seg, S);
            scat1(ca.y, i0 + 1, wp2, ticket, seg, S);
            scat1(ca.z, i0 + 2, wp2, ticket, seg, S);
            scat1(ca.w, i0 + 3, wp2, ticket, seg, S);
            scat1(cb.x, i0 + 4, wp2, ticket, seg, S);
            scat1(cb.y, i0 + 5, wp2, ticket, seg, S);
            scat1(cb.z, i0 + 6, wp2, ticket, seg, S);
            scat1(cb.w, i0 + 7, wp2, ticket, seg, S);
        }
        if (g == 0) {
            for (int i = n8 * 8; i < n; ++i)
                scat1(cellid[i], i, wp2, ticket, seg, S);
        }
    } else {
        if (g < n) {
            const float* p = pts + (size_t)g * 5;
            scat1(cell_of(p[0], p[1], p[2]), g, wp2, ticket, seg, S);
        }
    }
}

// One wave per voxel: rank by original index (stable), gather feats, write ALL
// 32 slots (zeros for empty ranks) + num_points. No output memset needed.
__global__ __launch_bounds__(256) void k_fill(const float* pts, const int* ticket,
                                              const int* seg, int S,
                                              float* out_vox, float* out_np) {
    __shared__ int slot[4][MAXP];
    int wave = threadIdx.x >> 6, lane = threadIdx.x & 63;
    int v = blockIdx.x * 4 + wave;     // MAXV % 4 == 0 -> always in range
    int ntot = ticket[(size_t)v * TPAD];
    int nn = min(ntot, S);             // S >= 32; P(cell count > S) ~ 0
    int m = min(nn, MAXP);
    int myidx = (lane < nn) ? seg[(size_t)v * S + lane] : 0x7fffffff;
    int rank = 0;
    for (int j = 0; j < nn; ++j) {
        int ej = __shfl(myidx, j, 64);
        rank += (ej < myidx) ? 1 : 0;
    }
    if (lane < nn && rank < MAXP) slot[wave][rank] = myidx;
    __syncthreads();   // order LDS scatter before readback (all threads reach)
    if (lane < MAXP) {
        float* dst = out_vox + ((size_t)v * MAXP + lane) * 5;
        if (lane < m) {
            const float* src = pts + (size_t)slot[wave][lane] * 5;
            #pragma unroll
            for (int k = 0; k < 5; ++k) dst[k] = bf16r(src[k]);
        } else {
            #pragma unroll
            for (int k = 0; k < 5; ++k) dst[k] = 0.0f;
        }
    }
    if (lane == 0) out_np[v] = bf16r((float)m);
}

extern "C" void kernel_launch(void* const* d_in, const int* in_sizes, int n_in,
                              void* d_out, int out_size, void* d_ws, size_t ws_size,
                              hipStream_t stream) {
    const float* pts = (const float*)d_in[0];
    int n = in_sizes[0] / 5;

    float* out = (float*)d_out;   // fp32 storage, bf16-precision values
    float* out_vox    = out;                                   // MAXV*32*5
    float* out_coords = out + (size_t)MAXV * MAXP * 5;         // MAXV*3
    float* out_np     = out_coords + (size_t)MAXV * 3;         // MAXV

    // ws ints: cellid[ncid]? + segbm[NSEG*NWP] + ticket[MAXV*TPAD]
    //          + wp2[2*NWORDS] + seg[MAXV*S]
    size_t ws_ints = ws_size / sizeof(int);
    size_t ncid = ((size_t)n + 3) & ~(size_t)3;   // keep segbm 16B-aligned
    const size_t fixed = (size_t)NSEG * NWP + (size_t)MAXV * TPAD
                       + 2 * (size_t)NWORDS;
    int S = 32; bool use_cid = false;
    {
        auto fits = [&](int s, bool cid) {
            return fixed + (size_t)MAXV * s + (cid ? ncid : 0) <= ws_ints;
        };
        struct Cfg { int s; bool cid; };
        const Cfg cfgs[] = {
            {64, true}, {48, true}, {40, true},
            {64, false}, {48, false}, {32, false},
        };
        for (const Cfg& c : cfgs) {
            if (fits(c.s, c.cid)) { S = c.s; use_cid = c.cid; break; }
        }
    }

    int* ws = (int*)d_ws;
    int* cellid        = use_cid ? ws : nullptr;                       // ncid (optional)
    unsigned* segbm    = (unsigned*)(ws + (use_cid ? ncid : 0));       // NSEG*NWP
    int* ticket        = (int*)(segbm + (size_t)NSEG * NWP);           // MAXV*TPAD
    int2* wp2          = (int2*)(ticket + (size_t)MAXV * TPAD);        // NWORDS (8B-aligned)
    int* seg           = (int*)(wp2 + NWORDS);                         // MAXV * S

    int nb  = (n + 255) / 256;
    int nb8 = (n / 8 + 255) / 256;
    k_zero<<<ZEROB, 256, 0, stream>>>(segbm);
    k_cell<<<CELLG, 1024, 0, stream>>>(pts, cellid, segbm, ticket, n);
    k_scan<<<SCANB, 256, 0, stream>>>(segbm, wp2, out_coords);
    k_scatter<<<(use_cid ? nb8 : nb), 256, 0, stream>>>(pts, cellid, wp2,
                                                        ticket, seg, S, n);
    k_fill<<<(MAXV + 3) / 4, 256, 0, stream>>>(pts, ticket, seg, S, out_vox, out_np);
}

// Round 10
// 147.192 us; speedup vs baseline: 1.3965x; 1.3965x over previous
//
#include <hip/hip_runtime.h>
#include <hip/hip_bf16.h>

#define NXC 440
#define NYC 500
#define GCELLS (NXC * NYC)              // 220000 (NZ = 1)
#define NWORDS ((GCELLS + 31) / 32)     // 6875 bitmap words (6875*32 == 220000)
#define MAXV 40000
#define MAXP 32
#define SCANB ((NWORDS + 255) / 256)    // 27 blocks for word-sliced scan
#define TPAD 16                         // ticket stride (ints): 1 counter / 64B line
#define CELLG 512                       // k_cell blocks (1024 thr, streaming)
#define ZEROB 64                        // k_zero blocks (cellflag + ticket)
#define NFLAGI (GCELLS / 4)             // cellflag as ints (220000 % 16 == 0)

// Expected outputs are bf16-quantized but stored as fp32: round-trip.
__device__ __forceinline__ float bf16r(float x) {
    return __bfloat162float(__float2bfloat16(x));
}

// Linear cell index exactly as the reference (fp32 ops). Invalid -> -1.
__device__ __forceinline__ int cell_of(float x, float y, float z) {
    bool valid = (x >= 0.0f) && (x < 70.4f) &&
                 (y >= -40.0f) && (y < 40.0f) &&
                 (z >= -3.0f) && (z < 1.0f);
    if (!valid) return -1;
    int cx = (int)floorf(x / 0.16f);
    int cy = (int)floorf((y + 40.0f) / 0.16f);
    // z in [-3,1) -> cz == 0 always (NZ = 1)
    cx = min(max(cx, 0), NXC - 1);
    cy = min(max(cy, 0), NYC - 1);
    return cy * NXC + cx;
}

// LSBs of the 4 bytes of u -> nibble (byte j -> bit j).
__device__ __forceinline__ unsigned nib4(unsigned u) {
    return (u | (u >> 7) | (u >> 14) | (u >> 21)) & 0xFu;
}

// Zero cellflag (220 KB) + ticket (2.5 MB); both consumed downstream.
__global__ __launch_bounds__(256) void k_zero(unsigned* cellflag, int* ticket) {
    int tid = blockIdx.x * 256 + threadIdx.x;
    int stride = ZEROB * 256;
    uint4* f4 = (uint4*)cellflag;
    for (int i = tid; i < NFLAGI / 4; i += stride)
        f4[i] = make_uint4(0u, 0u, 0u, 0u);
    int4* t4 = (int4*)ticket;
    for (int i = tid; i < MAXV * TPAD / 4; i += stride)
        t4[i] = make_int4(0, 0, 0, 0);
}

// Pass 1: plain byte store cellflag[cell]=1 (idempotent race; byte-granular
// dirty masks make cross-XCD writes safe per the HIP memory model). No LDS,
// no barriers, NO ATOMICS: R8 measured 2M scattered device atomics at 80 us
// w/ 70 MB HBM write (each random-line atomic = a memory-side transaction);
// plain scattered byte stores carry no coherence-point round trip.
__global__ __launch_bounds__(1024) void k_cell(const float* pts, int* cellid,
                                               unsigned char* cellflag, int n) {
    int tid = blockIdx.x * 1024 + threadIdx.x;
    int nq = n >> 2;                    // groups of 4 points
    int stride = CELLG * 1024;
    const float4* p4 = (const float4*)pts;
    for (int q = tid; q < nq; q += stride) {
        float4 f0 = p4[q * 5 + 0];      // floats 0..3   (pt0 xyzw0)
        float4 f1 = p4[q * 5 + 1];      // floats 4..7
        float4 f2 = p4[q * 5 + 2];      // floats 8..11
        float4 f3 = p4[q * 5 + 3];      // floats 12..15
        float4 f4 = p4[q * 5 + 4];      // floats 16..19
        int c0 = cell_of(f0.x, f0.y, f0.z);   // floats 0,1,2
        int c1 = cell_of(f1.y, f1.z, f1.w);   // floats 5,6,7
        int c2 = cell_of(f2.z, f2.w, f3.x);   // floats 10,11,12
        int c3 = cell_of(f3.w, f4.x, f4.y);   // floats 15,16,17
        if (cellid) ((int4*)cellid)[q] = make_int4(c0, c1, c2, c3);
        if (c0 >= 0) cellflag[c0] = 1;
        if (c1 >= 0) cellflag[c1] = 1;
        if (c2 >= 0) cellflag[c2] = 1;
        if (c3 >= 0) cellflag[c3] = 1;
    }
    // tail (n % 4 != 0): handled scalar by one thread
    if (tid == 0) {
        for (int i = nq * 4; i < n; ++i) {
            const float* p = pts + (size_t)i * 5;
            int c = cell_of(p[0], p[1], p[2]);
            if (cellid) cellid[i] = c;
            if (c >= 0) cellflag[c] = 1;
        }
    }
}

// Word-level exclusive scan over the byte-flag array (packed 32 bytes ->
// 1 word on the fly; flags are 0/1 so byte-sum tricks apply). Self-computed
// cross-block base -> fused (prefix, occword) int2 table; emit coords.
__global__ __launch_bounds__(256) void k_scan(const unsigned* cellflag,
                                              int2* wp2, float* out_coords) {
    int b = blockIdx.x, t = threadIdx.x;
    // cross-block base: count of set flags before this block's slice
    __shared__ int sb[256];
    int pre = 0;
    const uint4* f4 = (const uint4*)cellflag;   // 16 cells per uint4
    for (int i = t; i < b * 512; i += 256) {    // b*512 uint4 = b*256 words
        uint4 v = f4[i];
        unsigned s = v.x + v.y + v.z + v.w;     // per-byte sums <= 4: no carry
        pre += (int)((s * 0x01010101u) >> 24);  // sum of 4 byte-sums
    }
    sb[t] = pre;
    __syncthreads();
    for (int d = 128; d > 0; d >>= 1) {
        if (t < d) sb[t] += sb[t + d];
        __syncthreads();
    }
    int base = sb[0];
    // intra-block scan over this slice
    int w = b * 256 + t;
    unsigned o = 0u;
    if (w < NWORDS) {
        uint4 q0 = f4[w * 2], q1 = f4[w * 2 + 1];   // 32 bytes of word w
        o =  nib4(q0.x)        | (nib4(q0.y) << 4)  |
            (nib4(q0.z) << 8)  | (nib4(q0.w) << 12) |
            (nib4(q1.x) << 16) | (nib4(q1.y) << 20) |
            (nib4(q1.z) << 24) | (nib4(q1.w) << 28);
    }
    int c = __popc(o);
    __shared__ int s[256];
    s[t] = c;
    __syncthreads();
    for (int d = 1; d < 256; d <<= 1) {
        int v = (t >= d) ? s[t - d] : 0;
        __syncthreads();
        s[t] += v;
        __syncthreads();
    }
    int vid = base + (s[t] - c);
    if (w < NWORDS) {
        wp2[w] = make_int2(vid, (int)o);
        if (vid < MAXV) {
            unsigned m = o;
            while (m) {
                int bit = __ffs(m) - 1;
                m &= m - 1u;
                if (vid < MAXV) {
                    int cell = w * 32 + bit;
                    int cy = cell / NXC, cx = cell - cy * NXC;
                    float* oc = out_coords + (size_t)vid * 3;
                    oc[0] = 0.0f;
                    oc[1] = bf16r((float)cy);
                    oc[2] = bf16r((float)cx);
                }
                ++vid;
            }
        }
    }
}

__device__ __forceinline__ void scat1(int cell, int i, const int2* wp2,
                                      int* ticket, int* seg, int S) {
    if (cell < 0) return;
    int w = cell >> 5, b = cell & 31;
    int2 t2 = wp2[w];                   // 8B L2 load (55 KB table, L2-hot)
    int vid = t2.x + __popc(((unsigned)t2.y) & ((1u << b) - 1u));
    if (vid >= MAXV) return;
    int t = atomicAdd(&ticket[(size_t)vid * TPAD], 1);
    if (t < S) seg[(size_t)vid * S + t] = i;
}

// Scatter point indices into fixed-stride per-voxel segments, 8 pts/thread
// via 2x int4 cellid loads (8 independent lookup->atomic chains: latency ILP
// hides the L2 lookups -- R6's LDS-cached variant was neutral-to-negative).
__global__ __launch_bounds__(256) void k_scatter(const float* pts, const int* cellid,
                                                 const int2* wp2,
                                                 int* ticket, int* seg, int S, int n) {
    int g = blockIdx.x * 256 + threadIdx.x;
    int n8 = n >> 3;
    if (cellid) {
        if (g < n8) {
            const int4* c4 = (const int4*)cellid;
            int4 ca = c4[g * 2], cb = c4[g * 2 + 1];
            int i0 = g * 8;
            scat1(ca.x, i0 + 0, wp2, ticket, seg, S);
            scat1(ca.y, i0 + 1, wp2, ticket, seg, S);
            scat1(ca.z, i0 + 2, wp2, ticket, seg, S);
            scat1(ca.w, i0 + 3, wp2, ticket, seg, S);
            scat1(cb.x, i0 + 4, wp2, ticket, seg, S);
            scat1(cb.y, i0 + 5, wp2, ticket, seg, S);
            scat1(cb.z, i0 + 6, wp2, ticket, seg, S);
            scat1(cb.w, i0 + 7, wp2, ticket, seg, S);
        }
        if (g == 0) {
            for (int i = n8 * 8; i < n; ++i)
                scat1(cellid[i], i, wp2, ticket, seg, S);
        }
    } else {
        if (g < n) {
            const float* p = pts + (size_t)g * 5;
            scat1(cell_of(p[0], p[1], p[2]), g, wp2, ticket, seg, S);
        }
    }
}

// One wave per voxel: rank by original index (stable), gather feats, write ALL
// 32 slots (zeros for empty ranks) + num_points. No output memset needed.
__global__ __launch_bounds__(256) void k_fill(const float* pts, const int* ticket,
                                              const int* seg, int S,
                                              float* out_vox, float* out_np) {
    __shared__ int slot[4][MAXP];
    int wave = threadIdx.x >> 6, lane = threadIdx.x & 63;
    int v = blockIdx.x * 4 + wave;     // MAXV % 4 == 0 -> always in range
    int ntot = ticket[(size_t)v * TPAD];
    int nn = min(ntot, S);             // S >= 32; P(cell count > S) ~ 0
    int m = min(nn, MAXP);
    int myidx = (lane < nn) ? seg[(size_t)v * S + lane] : 0x7fffffff;
    int rank = 0;
    for (int j = 0; j < nn; ++j) {
        int ej = __shfl(myidx, j, 64);
        rank += (ej < myidx) ? 1 : 0;
    }
    if (lane < nn && rank < MAXP) slot[wave][rank] = myidx;
    __syncthreads();   // order LDS scatter before readback (all threads reach)
    if (lane < MAXP) {
        float* dst = out_vox + ((size_t)v * MAXP + lane) * 5;
        if (lane < m) {
            const float* src = pts + (size_t)slot[wave][lane] * 5;
            #pragma unroll
            for (int k = 0; k < 5; ++k) dst[k] = bf16r(src[k]);
        } else {
            #pragma unroll
            for (int k = 0; k < 5; ++k) dst[k] = 0.0f;
        }
    }
    if (lane == 0) out_np[v] = bf16r((float)m);
}

extern "C" void kernel_launch(void* const* d_in, const int* in_sizes, int n_in,
                              void* d_out, int out_size, void* d_ws, size_t ws_size,
                              hipStream_t stream) {
    const float* pts = (const float*)d_in[0];
    int n = in_sizes[0] / 5;

    float* out = (float*)d_out;   // fp32 storage, bf16-precision values
    float* out_vox    = out;                                   // MAXV*32*5
    float* out_coords = out + (size_t)MAXV * MAXP * 5;         // MAXV*3
    float* out_np     = out_coords + (size_t)MAXV * 3;         // MAXV

    // ws ints: cellid[ncid]? + cellflag[NFLAGI] + ticket[MAXV*TPAD]
    //          + wp2[2*NWORDS] + seg[MAXV*S]
    size_t ws_ints = ws_size / sizeof(int);
    size_t ncid = ((size_t)n + 3) & ~(size_t)3;   // keep cellflag 16B-aligned
    const size_t fixed = (size_t)NFLAGI + (size_t)MAXV * TPAD + 2 * (size_t)NWORDS;
    int S = 32; bool use_cid = false;
    {
        auto fits = [&](int s, bool cid) {
            return fixed + (size_t)MAXV * s + (cid ? ncid : 0) <= ws_ints;
        };
        struct Cfg { int s; bool cid; };
        const Cfg cfgs[] = {
            {64, true}, {48, true}, {40, true},
            {64, false}, {48, false}, {32, false},
        };
        for (const Cfg& c : cfgs) {
            if (fits(c.s, c.cid)) { S = c.s; use_cid = c.cid; break; }
        }
    }

    int* ws = (int*)d_ws;
    int* cellid        = use_cid ? ws : nullptr;                       // ncid (optional)
    unsigned* cellflag = (unsigned*)(ws + (use_cid ? ncid : 0));       // NFLAGI ints
    int* ticket        = (int*)(cellflag + NFLAGI);                    // MAXV*TPAD
    int2* wp2          = (int2*)(ticket + (size_t)MAXV * TPAD);        // NWORDS (8B-aligned)
    int* seg           = (int*)(wp2 + NWORDS);                         // MAXV * S

    int nb  = (n + 255) / 256;
    int nb8 = (n / 8 + 255) / 256;
    k_zero<<<ZEROB, 256, 0, stream>>>(cellflag, ticket);
    k_cell<<<CELLG, 1024, 0, stream>>>(pts, cellid, (unsigned char*)cellflag, n);
    k_scan<<<SCANB, 256, 0, stream>>>(cellflag, wp2, out_coords);
    k_scatter<<<(use_cid ? nb8 : nb), 256, 0, stream>>>(pts, cellid, wp2,
                                                        ticket, seg, S, n);
    k_fill<<<(MAXV + 3) / 4, 256, 0, stream>>>(pts, ticket, seg, S, out_vox, out_np);
}

// Round 11
// 139.228 us; speedup vs baseline: 1.4764x; 1.0572x over previous
//
#include <hip/hip_runtime.h>
#include <hip/hip_bf16.h>

#define NXC 440
#define NYC 500
#define GCELLS (NXC * NYC)              // 220000 (NZ = 1)
#define NWORDS ((GCELLS + 31) / 32)     // 6875 bitmap words (6875*32 == 220000)
#define MAXV 40000
#define MAXP 32
#define SCANB ((NWORDS + 255) / 256)    // 27 blocks for word-sliced scan
#define TPAD 16                         // ticket stride (ints): 1 counter / 64B line
#define CELLG 512                       // k_cell blocks (1024 thr, streaming)
#define ZEROB 128                       // k_zero blocks (cellflag + ticket)
#define NFLAGI (GCELLS / 4)             // cellflag as ints (220000 % 16 == 0)

// Expected outputs are bf16-quantized but stored as fp32: round-trip.
__device__ __forceinline__ float bf16r(float x) {
    return __bfloat162float(__float2bfloat16(x));
}

// Linear cell index exactly as the reference (fp32 ops). Invalid -> -1.
__device__ __forceinline__ int cell_of(float x, float y, float z) {
    bool valid = (x >= 0.0f) && (x < 70.4f) &&
                 (y >= -40.0f) && (y < 40.0f) &&
                 (z >= -3.0f) && (z < 1.0f);
    if (!valid) return -1;
    int cx = (int)floorf(x / 0.16f);
    int cy = (int)floorf((y + 40.0f) / 0.16f);
    // z in [-3,1) -> cz == 0 always (NZ = 1)
    cx = min(max(cx, 0), NXC - 1);
    cy = min(max(cy, 0), NYC - 1);
    return cy * NXC + cx;
}

// LSBs of the 4 bytes of u -> nibble (byte j -> bit j).
__device__ __forceinline__ unsigned nib4(unsigned u) {
    return (u | (u >> 7) | (u >> 14) | (u >> 21)) & 0xFu;
}

// Zero cellflag (220 KB) + ticket (2.5 MB); both consumed downstream.
__global__ __launch_bounds__(256) void k_zero(unsigned* cellflag, int* ticket) {
    int tid = blockIdx.x * 256 + threadIdx.x;
    int stride = ZEROB * 256;
    uint4* f4 = (uint4*)cellflag;
    for (int i = tid; i < NFLAGI / 4; i += stride)
        f4[i] = make_uint4(0u, 0u, 0u, 0u);
    int4* t4 = (int4*)ticket;
    for (int i = tid; i < MAXV * TPAD / 4; i += stride)
        t4[i] = make_int4(0, 0, 0, 0);
}

// Pass 1: plain byte store cellflag[cell]=1 (idempotent race; byte-granular
// dirty masks make cross-XCD writes safe). No LDS, no barriers, NO ATOMICS
// (R8: 2M scattered device atomics = 80 us / 70 MB HBM write; R10 verified
// this byte-store form passes with absmax=0).
__global__ __launch_bounds__(1024) void k_cell(const float* pts, int* cellid,
                                               unsigned char* cellflag, int n) {
    int tid = blockIdx.x * 1024 + threadIdx.x;
    int nq = n >> 2;                    // groups of 4 points
    int stride = CELLG * 1024;
    const float4* p4 = (const float4*)pts;
    for (int q = tid; q < nq; q += stride) {
        float4 f0 = p4[q * 5 + 0];      // floats 0..3   (pt0 xyzw0)
        float4 f1 = p4[q * 5 + 1];      // floats 4..7
        float4 f2 = p4[q * 5 + 2];      // floats 8..11
        float4 f3 = p4[q * 5 + 3];      // floats 12..15
        float4 f4 = p4[q * 5 + 4];      // floats 16..19
        int c0 = cell_of(f0.x, f0.y, f0.z);   // floats 0,1,2
        int c1 = cell_of(f1.y, f1.z, f1.w);   // floats 5,6,7
        int c2 = cell_of(f2.z, f2.w, f3.x);   // floats 10,11,12
        int c3 = cell_of(f3.w, f4.x, f4.y);   // floats 15,16,17
        if (cellid) ((int4*)cellid)[q] = make_int4(c0, c1, c2, c3);
        if (c0 >= 0) cellflag[c0] = 1;
        if (c1 >= 0) cellflag[c1] = 1;
        if (c2 >= 0) cellflag[c2] = 1;
        if (c3 >= 0) cellflag[c3] = 1;
    }
    // tail (n % 4 != 0): handled scalar by one thread
    if (tid == 0) {
        for (int i = nq * 4; i < n; ++i) {
            const float* p = pts + (size_t)i * 5;
            int c = cell_of(p[0], p[1], p[2]);
            if (cellid) cellid[i] = c;
            if (c >= 0) cellflag[c] = 1;
        }
    }
}

// Word-level exclusive scan over the byte-flag array (packed 32 bytes ->
// 1 word on the fly; flags are 0/1 so byte-sum tricks apply). Self-computed
// cross-block base -> fused (prefix, occword) int2 table; emit coords.
__global__ __launch_bounds__(256) void k_scan(const unsigned* cellflag,
                                              int2* wp2, float* out_coords) {
    int b = blockIdx.x, t = threadIdx.x;
    // cross-block base: count of set flags before this block's slice
    __shared__ int sb[256];
    int pre = 0;
    const uint4* f4 = (const uint4*)cellflag;   // 16 cells per uint4
    for (int i = t; i < b * 512; i += 256) {    // b*512 uint4 = b*256 words
        uint4 v = f4[i];
        unsigned s = v.x + v.y + v.z + v.w;     // per-byte sums <= 4: no carry
        pre += (int)((s * 0x01010101u) >> 24);  // sum of 4 byte-sums
    }
    sb[t] = pre;
    __syncthreads();
    for (int d = 128; d > 0; d >>= 1) {
        if (t < d) sb[t] += sb[t + d];
        __syncthreads();
    }
    int base = sb[0];
    // intra-block scan over this slice
    int w = b * 256 + t;
    unsigned o = 0u;
    if (w < NWORDS) {
        uint4 q0 = f4[w * 2], q1 = f4[w * 2 + 1];   // 32 bytes of word w
        o =  nib4(q0.x)        | (nib4(q0.y) << 4)  |
            (nib4(q0.z) << 8)  | (nib4(q0.w) << 12) |
            (nib4(q1.x) << 16) | (nib4(q1.y) << 20) |
            (nib4(q1.z) << 24) | (nib4(q1.w) << 28);
    }
    int c = __popc(o);
    __shared__ int s[256];
    s[t] = c;
    __syncthreads();
    for (int d = 1; d < 256; d <<= 1) {
        int v = (t >= d) ? s[t - d] : 0;
        __syncthreads();
        s[t] += v;
        __syncthreads();
    }
    int vid = base + (s[t] - c);
    if (w < NWORDS) {
        wp2[w] = make_int2(vid, (int)o);
        if (vid < MAXV) {
            unsigned m = o;
            while (m) {
                int bit = __ffs(m) - 1;
                m &= m - 1u;
                if (vid < MAXV) {
                    int cell = w * 32 + bit;
                    int cy = cell / NXC, cx = cell - cy * NXC;
                    float* oc = out_coords + (size_t)vid * 3;
                    oc[0] = 0.0f;
                    oc[1] = bf16r((float)cy);
                    oc[2] = bf16r((float)cx);
                }
                ++vid;
            }
        }
    }
}

__device__ __forceinline__ void scat1(int cell, int i, const int2* wp2,
                                      int* ticket, int* seg, int S) {
    if (cell < 0) return;
    int w = cell >> 5, b = cell & 31;
    int2 t2 = wp2[w];                   // 8B L2 load (55 KB table, L2-hot)
    int vid = t2.x + __popc(((unsigned)t2.y) & ((1u << b) - 1u));
    if (vid >= MAXV) return;
    int t = atomicAdd(&ticket[(size_t)vid * TPAD], 1);
    if (t < S) seg[(size_t)vid * S + t] = i;
}

// Scatter point indices into fixed-stride per-voxel segments, 8 pts/thread
// via 2x int4 cellid loads (8 independent lookup->atomic chains: latency ILP
// hides the L2 lookups -- R6's LDS-cached variant was neutral-to-negative).
__global__ __launch_bounds__(256) void k_scatter(const float* pts, const int* cellid,
                                                 const int2* wp2,
                                                 int* ticket, int* seg, int S, int n) {
    int g = blockIdx.x * 256 + threadIdx.x;
    int n8 = n >> 3;
    if (cellid) {
        if (g < n8) {
            const int4* c4 = (const int4*)cellid;
            int4 ca = c4[g * 2], cb = c4[g * 2 + 1];
            int i0 = g * 8;
            scat1(ca.x, i0 + 0, wp2, ticket, seg, S);
            scat1(ca.y, i0 + 1, wp2, ticket, seg, S);
            scat1(ca.z, i0 + 2, wp2, ticket, seg, S);
            scat1(ca.w, i0 + 3, wp2, ticket, seg, S);
            scat1(cb.x, i0 + 4, wp2, ticket, seg, S);
            scat1(cb.y, i0 + 5, wp2, ticket, seg, S);
            scat1(cb.z, i0 + 6, wp2, ticket, seg, S);
            scat1(cb.w, i0 + 7, wp2, ticket, seg, S);
        }
        if (g == 0) {
            for (int i = n8 * 8; i < n; ++i)
                scat1(cellid[i], i, wp2, ticket, seg, S);
        }
    } else {
        if (g < n) {
            const float* p = pts + (size_t)g * 5;
            scat1(cell_of(p[0], p[1], p[2]), g, wp2, ticket, seg, S);
        }
    }
}

// One wave per voxel: rank by original index (stable), gather feats into LDS,
// then block-wide coalesced float4 stream-out (was: 5 scalar stores/lane at
// 20B stride = 640 scattered dwords/block; now 160 coalesced dwordx4).
__global__ __launch_bounds__(256) void k_fill(const float* pts, const int* ticket,
                                              const int* seg, int S,
                                              float* out_vox, float* out_np) {
    __shared__ int slot[4][MAXP];
    __shared__ float feats[4 * MAXP * 5];   // 10 KB staging (4 voxels x 160 f)
    __shared__ float npst[4];
    int wave = threadIdx.x >> 6, lane = threadIdx.x & 63;
    int v = blockIdx.x * 4 + wave;     // MAXV % 4 == 0 -> always in range
    int ntot = ticket[(size_t)v * TPAD];
    int nn = min(ntot, S);             // S >= 32; P(cell count > S) ~ 0
    int m = min(nn, MAXP);
    int myidx = (lane < nn) ? seg[(size_t)v * S + lane] : 0x7fffffff;
    int rank = 0;
    for (int j = 0; j < nn; ++j) {
        int ej = __shfl(myidx, j, 64);
        rank += (ej < myidx) ? 1 : 0;
    }
    if (lane < nn && rank < MAXP) slot[wave][rank] = myidx;
    __syncthreads();   // order LDS scatter before readback (all threads reach)
    if (lane < MAXP) {
        // stride-5 dword LDS writes: gcd(5,32)=1 -> bank-conflict-free
        float* f = feats + (wave * MAXP + lane) * 5;
        if (lane < m) {
            const float* src = pts + (size_t)slot[wave][lane] * 5;
            #pragma unroll
            for (int k = 0; k < 5; ++k) f[k] = bf16r(src[k]);
        } else {
            #pragma unroll
            for (int k = 0; k < 5; ++k) f[k] = 0.0f;
        }
    }
    if (lane == 0) npst[wave] = bf16r((float)m);
    __syncthreads();
    // coalesced block output: 4 voxels x 160 floats = 640 float4 per block
    float4* dst4 = (float4*)(out_vox + (size_t)blockIdx.x * (4 * MAXP * 5));
    const float4* s4 = (const float4*)feats;
    #pragma unroll
    for (int i = threadIdx.x; i < 4 * MAXP * 5 / 4; i += 256)
        dst4[i] = s4[i];
    if (threadIdx.x < 4) out_np[blockIdx.x * 4 + threadIdx.x] = npst[threadIdx.x];
}

extern "C" void kernel_launch(void* const* d_in, const int* in_sizes, int n_in,
                              void* d_out, int out_size, void* d_ws, size_t ws_size,
                              hipStream_t stream) {
    const float* pts = (const float*)d_in[0];
    int n = in_sizes[0] / 5;

    float* out = (float*)d_out;   // fp32 storage, bf16-precision values
    float* out_vox    = out;                                   // MAXV*32*5
    float* out_coords = out + (size_t)MAXV * MAXP * 5;         // MAXV*3
    float* out_np     = out_coords + (size_t)MAXV * 3;         // MAXV

    // ws ints: cellid[ncid]? + cellflag[NFLAGI] + ticket[MAXV*TPAD]
    //          + wp2[2*NWORDS] + seg[MAXV*S]
    size_t ws_ints = ws_size / sizeof(int);
    size_t ncid = ((size_t)n + 3) & ~(size_t)3;   // keep cellflag 16B-aligned
    const size_t fixed = (size_t)NFLAGI + (size_t)MAXV * TPAD + 2 * (size_t)NWORDS;
    int S = 32; bool use_cid = false;
    {
        auto fits = [&](int s, bool cid) {
            return fixed + (size_t)MAXV * s + (cid ? ncid : 0) <= ws_ints;
        };
        struct Cfg { int s; bool cid; };
        const Cfg cfgs[] = {
            {64, true}, {48, true}, {40, true},
            {64, false}, {48, false}, {32, false},
        };
        for (const Cfg& c : cfgs) {
            if (fits(c.s, c.cid)) { S = c.s; use_cid = c.cid; break; }
        }
    }

    int* ws = (int*)d_ws;
    int* cellid        = use_cid ? ws : nullptr;                       // ncid (optional)
    unsigned* cellflag = (unsigned*)(ws + (use_cid ? ncid : 0));       // NFLAGI ints
    int* ticket        = (int*)(cellflag + NFLAGI);                    // MAXV*TPAD
    int2* wp2          = (int2*)(ticket + (size_t)MAXV * TPAD);        // NWORDS (8B-aligned)
    int* seg           = (int*)(wp2 + NWORDS);                         // MAXV * S

    int nb  = (n + 255) / 256;
    int nb8 = (n / 8 + 255) / 256;
    k_zero<<<ZEROB, 256, 0, stream>>>(cellflag, ticket);
    k_cell<<<CELLG, 1024, 0, stream>>>(pts, cellid, (unsigned char*)cellflag, n);
    k_scan<<<SCANB, 256, 0, stream>>>(cellflag, wp2, out_coords);
    k_scatter<<<(use_cid ? nb8 : nb), 256, 0, stream>>>(pts, cellid, wp2,
                                                        ticket, seg, S, n);
    k_fill<<<(MAXV + 3) / 4, 256, 0, stream>>>(pts, ticket, seg, S, out_vox, out_np);
}

// Round 12
// 138.351 us; speedup vs baseline: 1.4857x; 1.0063x over previous
//
#include <hip/hip_runtime.h>
#include <hip/hip_bf16.h>

#define NXC 440
#define NYC 500
#define GCELLS (NXC * NYC)              // 220000 (NZ = 1)
#define NWORDS ((GCELLS + 31) / 32)     // 6875 bitmap words (6875*32 == 220000)
#define MAXV 40000
#define MAXP 32
#define SCANB ((NWORDS + 255) / 256)    // 27 blocks for word-sliced scan
#define TPAD 16                         // ticket stride (ints): 1 counter / 64B line
#define CELLG 512                       // k_cell blocks (1024 thr, streaming)
#define ZEROB 128                       // k_zero blocks (cellflag + ticket)
#define NFLAGI (GCELLS / 4)             // cellflag as ints (220000 % 16 == 0)
#define RECI 8                          // seg record stride (ints): idx + 5 feats, 32B-aligned

// Expected outputs are bf16-quantized but stored as fp32: round-trip.
__device__ __forceinline__ float bf16r(float x) {
    return __bfloat162float(__float2bfloat16(x));
}

// Linear cell index exactly as the reference (fp32 ops). Invalid -> -1.
__device__ __forceinline__ int cell_of(float x, float y, float z) {
    bool valid = (x >= 0.0f) && (x < 70.4f) &&
                 (y >= -40.0f) && (y < 40.0f) &&
                 (z >= -3.0f) && (z < 1.0f);
    if (!valid) return -1;
    int cx = (int)floorf(x / 0.16f);
    int cy = (int)floorf((y + 40.0f) / 0.16f);
    // z in [-3,1) -> cz == 0 always (NZ = 1)
    cx = min(max(cx, 0), NXC - 1);
    cy = min(max(cy, 0), NYC - 1);
    return cy * NXC + cx;
}

// LSBs of the 4 bytes of u -> nibble (byte j -> bit j).
__device__ __forceinline__ unsigned nib4(unsigned u) {
    return (u | (u >> 7) | (u >> 14) | (u >> 21)) & 0xFu;
}

// Static-index access into a float4[10] register block (unroll-only: i must
// fold to a constant so SROA keeps it in VGPRs -- no scratch).
__device__ __forceinline__ float fget(const float4 (&r)[10], int i) {
    switch (i & 3) {
        case 0:  return r[i >> 2].x;
        case 1:  return r[i >> 2].y;
        case 2:  return r[i >> 2].z;
        default: return r[i >> 2].w;
    }
}

// Zero cellflag (220 KB) + ticket (2.5 MB); both consumed downstream.
__global__ __launch_bounds__(256) void k_zero(unsigned* cellflag, int* ticket) {
    int tid = blockIdx.x * 256 + threadIdx.x;
    int stride = ZEROB * 256;
    uint4* f4 = (uint4*)cellflag;
    for (int i = tid; i < NFLAGI / 4; i += stride)
        f4[i] = make_uint4(0u, 0u, 0u, 0u);
    int4* t4 = (int4*)ticket;
    for (int i = tid; i < MAXV * TPAD / 4; i += stride)
        t4[i] = make_int4(0, 0, 0, 0);
}

// Pass 1: pure flag stream -- plain byte store cellflag[cell]=1 (idempotent
// race; byte-granular dirty masks, verified R10/R11 absmax=0). No cellid
// write: k_scatter recomputes cells from pts (L3-hot re-read).
__global__ __launch_bounds__(1024) void k_cell(const float* pts,
                                               unsigned char* cellflag, int n) {
    int tid = blockIdx.x * 1024 + threadIdx.x;
    int nq = n >> 2;                    // groups of 4 points
    int stride = CELLG * 1024;
    const float4* p4 = (const float4*)pts;
    for (int q = tid; q < nq; q += stride) {
        float4 f0 = p4[q * 5 + 0];      // floats 0..3   (pt0 xyzw0)
        float4 f1 = p4[q * 5 + 1];      // floats 4..7
        float4 f2 = p4[q * 5 + 2];      // floats 8..11
        float4 f3 = p4[q * 5 + 3];      // floats 12..15
        float4 f4 = p4[q * 5 + 4];      // floats 16..19
        int c0 = cell_of(f0.x, f0.y, f0.z);   // floats 0,1,2
        int c1 = cell_of(f1.y, f1.z, f1.w);   // floats 5,6,7
        int c2 = cell_of(f2.z, f2.w, f3.x);   // floats 10,11,12
        int c3 = cell_of(f3.w, f4.x, f4.y);   // floats 15,16,17
        if (c0 >= 0) cellflag[c0] = 1;
        if (c1 >= 0) cellflag[c1] = 1;
        if (c2 >= 0) cellflag[c2] = 1;
        if (c3 >= 0) cellflag[c3] = 1;
    }
    // tail (n % 4 != 0): handled scalar by one thread
    if (tid == 0) {
        for (int i = nq * 4; i < n; ++i) {
            const float* p = pts + (size_t)i * 5;
            int c = cell_of(p[0], p[1], p[2]);
            if (c >= 0) cellflag[c] = 1;
        }
    }
}

// Word-level exclusive scan over the byte-flag array (packed 32 bytes ->
// 1 word on the fly). Self-computed cross-block base -> fused
// (prefix, occword) int2 table; emit coords.
__global__ __launch_bounds__(256) void k_scan(const unsigned* cellflag,
                                              int2* wp2, float* out_coords) {
    int b = blockIdx.x, t = threadIdx.x;
    // cross-block base: count of set flags before this block's slice
    __shared__ int sb[256];
    int pre = 0;
    const uint4* f4 = (const uint4*)cellflag;   // 16 cells per uint4
    for (int i = t; i < b * 512; i += 256) {    // b*512 uint4 = b*256 words
        uint4 v = f4[i];
        unsigned s = v.x + v.y + v.z + v.w;     // per-byte sums <= 4: no carry
        pre += (int)((s * 0x01010101u) >> 24);  // sum of 4 byte-sums
    }
    sb[t] = pre;
    __syncthreads();
    for (int d = 128; d > 0; d >>= 1) {
        if (t < d) sb[t] += sb[t + d];
        __syncthreads();
    }
    int base = sb[0];
    // intra-block scan over this slice
    int w = b * 256 + t;
    unsigned o = 0u;
    if (w < NWORDS) {
        uint4 q0 = f4[w * 2], q1 = f4[w * 2 + 1];   // 32 bytes of word w
        o =  nib4(q0.x)        | (nib4(q0.y) << 4)  |
            (nib4(q0.z) << 8)  | (nib4(q0.w) << 12) |
            (nib4(q1.x) << 16) | (nib4(q1.y) << 20) |
            (nib4(q1.z) << 24) | (nib4(q1.w) << 28);
    }
    int c = __popc(o);
    __shared__ int s[256];
    s[t] = c;
    __syncthreads();
    for (int d = 1; d < 256; d <<= 1) {
        int v = (t >= d) ? s[t - d] : 0;
        __syncthreads();
        s[t] += v;
        __syncthreads();
    }
    int vid = base + (s[t] - c);
    if (w < NWORDS) {
        wp2[w] = make_int2(vid, (int)o);
        if (vid < MAXV) {
            unsigned m = o;
            while (m) {
                int bit = __ffs(m) - 1;
                m &= m - 1u;
                if (vid < MAXV) {
                    int cell = w * 32 + bit;
                    int cy = cell / NXC, cx = cell - cy * NXC;
                    float* oc = out_coords + (size_t)vid * 3;
                    oc[0] = 0.0f;
                    oc[1] = bf16r((float)cy);
                    oc[2] = bf16r((float)cx);
                }
                ++vid;
            }
        }
    }
}

// Ticket + 32B record store {idx, bf16r(f0..f4)}: plain stores (no coherence
// round trip -- R8 showed scattered ATOMICS cost 35B/op memory-side; these
// are fire-and-forget with no dependent consumer until k_fill).
__device__ __forceinline__ void scat_feat(int cell, int i,
                                          float f0, float f1, float f2,
                                          float f3, float f4,
                                          const int2* wp2, int* ticket,
                                          int* seg, int S) {
    if (cell < 0) return;
    int w = cell >> 5, b = cell & 31;
    int2 t2 = wp2[w];                   // 8B L2 load (55 KB table, L2-hot)
    int vid = t2.x + __popc(((unsigned)t2.y) & ((1u << b) - 1u));
    if (vid >= MAXV) return;
    int t = atomicAdd(&ticket[(size_t)vid * TPAD], 1);
    if (t < S) {
        int* r = seg + ((size_t)vid * S + t) * RECI;    // 32B-aligned
        int4 a, bb;
        a.x = i;
        a.y = __float_as_int(bf16r(f0));
        a.z = __float_as_int(bf16r(f1));
        a.w = __float_as_int(bf16r(f2));
        bb.x = __float_as_int(bf16r(f3));
        bb.y = __float_as_int(bf16r(f4));
        bb.z = 0; bb.w = 0;
        ((int4*)r)[0] = a;
        ((int4*)r)[1] = bb;
    }
}

// Scatter: 8 pts/thread read CONTIGUOUSLY (10x float4, coalesced, L3-hot),
// cells recomputed (no cellid array), 8 independent lookup->atomic->store
// chains. Features travel inside the seg records so k_fill never gathers.
__global__ __launch_bounds__(256) void k_scatter(const float* pts,
                                                 const int2* wp2, int* ticket,
                                                 int* seg, int S, int n) {
    int g = blockIdx.x * 256 + threadIdx.x;
    int n8 = n >> 3;
    if (g < n8) {
        const float4* p4 = (const float4*)pts;
        float4 r[10];
        #pragma unroll
        for (int k = 0; k < 10; ++k) r[k] = p4[(size_t)g * 10 + k];
        int i0 = g * 8;
        #pragma unroll
        for (int j = 0; j < 8; ++j) {
            float x  = fget(r, 5 * j + 0), y  = fget(r, 5 * j + 1);
            float z  = fget(r, 5 * j + 2), w3 = fget(r, 5 * j + 3);
            float w4 = fget(r, 5 * j + 4);
            int c = cell_of(x, y, z);
            scat_feat(c, i0 + j, x, y, z, w3, w4, wp2, ticket, seg, S);
        }
    }
    if (g == 0) {                       // tail (n % 8 != 0)
        for (int i = n8 * 8; i < n; ++i) {
            const float* p = pts + (size_t)i * 5;
            int c = cell_of(p[0], p[1], p[2]);
            scat_feat(c, i, p[0], p[1], p[2], p[3], p[4], wp2, ticket, seg, S);
        }
    }
}

// One wave per voxel: read records COALESCED (2x int4/lane), rank by original
// index via shfl (stable), stage by rank in LDS, block-wide float4 stream-out.
// No random point gather (features arrived inside the records).
__global__ __launch_bounds__(256) void k_fill(const int* ticket, const int* seg,
                                              int S, float* out_vox, float* out_np) {
    __shared__ float feats[4 * MAXP * 5];   // 10 KB staging (4 voxels x 160 f)
    __shared__ float npst[4];
    int wave = threadIdx.x >> 6, lane = threadIdx.x & 63;
    int v = blockIdx.x * 4 + wave;     // MAXV % 4 == 0 -> always in range
    int ntot = ticket[(size_t)v * TPAD];
    int nn = min(ntot, S);             // S >= 32; P(cell count > S) ~ 0
    int m = min(nn, MAXP);
    int myidx = 0x7fffffff;
    float f0 = 0.f, f1 = 0.f, f2 = 0.f, f3 = 0.f, f4 = 0.f;
    if (lane < nn) {
        const int4* rp = (const int4*)(seg + ((size_t)v * S + lane) * RECI);
        int4 a = rp[0], b = rp[1];
        myidx = a.x;
        f0 = __int_as_float(a.y); f1 = __int_as_float(a.z);
        f2 = __int_as_float(a.w);
        f3 = __int_as_float(b.x); f4 = __int_as_float(b.y);
    }
    int rank = 0;
    for (int j = 0; j < nn; ++j) {
        int ej = __shfl(myidx, j, 64);
        rank += (ej < myidx) ? 1 : 0;
    }
    // zero staging, then rank-scatter: both per-wave regions, LDS is
    // program-ordered within a wave -> no barrier needed between them
    if (lane < MAXP) {
        float* d = feats + (wave * MAXP + lane) * 5;
        d[0] = d[1] = d[2] = d[3] = d[4] = 0.0f;
    }
    if (lane < nn && rank < MAXP) {
        float* d = feats + (wave * MAXP + rank) * 5;   // stride 5: conflict-free
        d[0] = f0; d[1] = f1; d[2] = f2; d[3] = f3; d[4] = f4;
    }
    if (lane == 0) npst[wave] = bf16r((float)m);
    __syncthreads();
    // coalesced block output: 4 voxels x 160 floats = 160 float4 per block
    float4* dst4 = (float4*)(out_vox + (size_t)blockIdx.x * (4 * MAXP * 5));
    const float4* s4 = (const float4*)feats;
    #pragma unroll
    for (int i = threadIdx.x; i < 4 * MAXP * 5 / 4; i += 256)
        dst4[i] = s4[i];
    if (threadIdx.x < 4) out_np[blockIdx.x * 4 + threadIdx.x] = npst[threadIdx.x];
}

extern "C" void kernel_launch(void* const* d_in, const int* in_sizes, int n_in,
                              void* d_out, int out_size, void* d_ws, size_t ws_size,
                              hipStream_t stream) {
    const float* pts = (const float*)d_in[0];
    int n = in_sizes[0] / 5;

    float* out = (float*)d_out;   // fp32 storage, bf16-precision values
    float* out_vox    = out;                                   // MAXV*32*5
    float* out_coords = out + (size_t)MAXV * MAXP * 5;         // MAXV*3
    float* out_np     = out_coords + (size_t)MAXV * 3;         // MAXV

    // ws ints: cellflag[NFLAGI] + ticket[MAXV*TPAD] + wp2[2*NWORDS]
    //          + seg[MAXV*S*RECI]
    size_t ws_ints = ws_size / sizeof(int);
    const size_t fixed = (size_t)NFLAGI + (size_t)MAXV * TPAD + 2 * (size_t)NWORDS;
    int S = 32;
    {
        auto fits = [&](int s) {
            return fixed + (size_t)MAXV * s * RECI <= ws_ints;
        };
        const int scand[] = {64, 48, 32};
        for (int s : scand) { if (fits(s)) { S = s; break; } }
    }

    int* ws = (int*)d_ws;
    unsigned* cellflag = (unsigned*)ws;                                // NFLAGI ints
    int* ticket        = (int*)(cellflag + NFLAGI);                    // MAXV*TPAD
    int2* wp2          = (int2*)(ticket + (size_t)MAXV * TPAD);        // NWORDS (8B-aligned)
    int* seg           = (int*)(wp2 + NWORDS);                         // MAXV*S*RECI (32B-aligned)

    int nb8 = (n / 8 + 255) / 256;
    if (nb8 < 1) nb8 = 1;
    k_zero<<<ZEROB, 256, 0, stream>>>(cellflag, ticket);
    k_cell<<<CELLG, 1024, 0, stream>>>(pts, (unsigned char*)cellflag, n);
    k_scan<<<SCANB, 256, 0, stream>>>(cellflag, wp2, out_coords);
    k_scatter<<<nb8, 256, 0, stream>>>(pts, wp2, ticket, seg, S, n);
    k_fill<<<(MAXV + 3) / 4, 256, 0, stream>>>(ticket, seg, S, out_vox, out_np);
}